// Round 1
// 263.047 us; speedup vs baseline: 1.0002x; 1.0002x over previous
//
#include <hip/hip_runtime.h>
#include <math.h>

#define BN 8
#define CN 64
#define HN 256
#define WN 256
#define HWN (HN * WN)          // 65536
#define NPIX (BN * HWN)        // 524288 pixels (b,h,w)
#define NTOT (BN * CN * HWN)   // 33554432 elements

struct DogK { float k[25]; };  // gk1 - gk2, 5x5 row-major

// Kernel 1: gray[b,h,w] = mean_c x[b,c,h,w].
// 4 waves per block, each wave sums 16 channels for the same 64 float4-pixels;
// LDS combine. 2048 blocks -> 8 blocks/CU -> 32 waves/CU (vs 8 before).
__global__ __launch_bounds__(256) void gray_kernel(const float* __restrict__ x,
                                                   float* __restrict__ gray) {
    const int t    = threadIdx.x;
    const int lane = t & 63;
    const int g    = t >> 6;                    // channel group 0..3
    const int pix4 = blockIdx.x * 64 + lane;    // float4-pixel index (exact: 2048*64 = NPIX/4)
    const int p4   = pix4 * 4;
    const int b    = p4 >> 16;                  // / HWN
    const int hw   = p4 & (HWN - 1);

    const float4* xp = (const float4*)(x + ((size_t)(b * CN + g * 16)) * HWN + hw);
    float4 acc = make_float4(0.f, 0.f, 0.f, 0.f);
    #pragma unroll
    for (int c = 0; c < 16; ++c) {
        float4 v = xp[c * (HWN / 4)];
        acc.x += v.x; acc.y += v.y; acc.z += v.z; acc.w += v.w;
    }

    __shared__ float4 red[4][64];
    red[g][lane] = acc;
    __syncthreads();
    if (t < 64) {
        float4 a0 = red[0][lane], a1 = red[1][lane], a2 = red[2][lane], a3 = red[3][lane];
        const float s = 1.0f / (float)CN;
        float4 o;
        o.x = (a0.x + a1.x + a2.x + a3.x) * s;
        o.y = (a0.y + a1.y + a2.y + a3.y) * s;
        o.z = (a0.z + a1.z + a2.z + a3.z) * s;
        o.w = (a0.w + a1.w + a2.w + a3.w) * s;
        *(float4*)(gray + p4) = o;
    }
}

// Kernel 2 (fused): dog = conv5x5(gray, zero-pad) -> sobel(zero-pad of dog) -> mag
//                   -> sigmoid gate -> att1 = 1 + att.
// One 16x16 output tile per block. Gray tile (halo 3) and dog tile (halo 1) in LDS.
// Zero-pad semantics of BOTH conv stages preserved exactly (dog outside image = 0).
__global__ __launch_bounds__(256) void att_fused(const float* __restrict__ gray,
                                                 float* __restrict__ att1,
                                                 const float* __restrict__ gw,
                                                 const float* __restrict__ gb,
                                                 DogK dk) {
    __shared__ float sG[22][23];   // gray tile + halo 3 (pad col to 23)
    __shared__ float sD[18][19];   // dog tile + halo 1

    const int t  = threadIdx.x;
    const int h0 = blockIdx.y * 16;
    const int w0 = blockIdx.x * 16;
    const int b  = blockIdx.z;
    const float* gbase = gray + b * HWN;

    // Stage gray (22x22 region, zero outside image).
    for (int i = t; i < 22 * 22; i += 256) {
        int gy = i / 22, gx = i - gy * 22;
        int h = h0 + gy - 3, w = w0 + gx - 3;
        sG[gy][gx] = (h >= 0 && h < HN && w >= 0 && w < WN) ? gbase[h * WN + w] : 0.f;
    }
    __syncthreads();

    // dog on 18x18 (tile + halo 1); positions outside image forced to 0
    // (matches reference: sobel zero-pads the dog map).
    for (int i = t; i < 18 * 18; i += 256) {
        int dy = i / 18, dx = i - dy * 18;
        int h = h0 + dy - 1, w = w0 + dx - 1;
        float acc = 0.f;
        if (h >= 0 && h < HN && w >= 0 && w < WN) {
            #pragma unroll
            for (int ki = 0; ki < 5; ++ki)
                #pragma unroll
                for (int kj = 0; kj < 5; ++kj)
                    acc += dk.k[ki * 5 + kj] * sG[dy + ki][dx + kj];
        }
        sD[dy][dx] = acc;
    }
    __syncthreads();

    // Sobel + magnitude + gate for the 16x16 interior.
    const int tx = t & 15, ty = t >> 4;
    float v00 = sD[ty    ][tx], v01 = sD[ty    ][tx + 1], v02 = sD[ty    ][tx + 2];
    float v10 = sD[ty + 1][tx],                            v12 = sD[ty + 1][tx + 2];
    float v20 = sD[ty + 2][tx], v21 = sD[ty + 2][tx + 1], v22 = sD[ty + 2][tx + 2];
    float gxv = (v02 - v00) + 2.f * (v12 - v10) + (v22 - v20);
    float gyv = (v20 - v00) + 2.f * (v21 - v01) + (v22 - v02);
    float mag = sqrtf(gxv * gxv + gyv * gyv + 1e-6f);
    float z = mag * gw[0] + gb[0];
    float a = 1.f / (1.f + expf(-z));
    att1[b * HWN + (h0 + ty) * WN + (w0 + tx)] = 1.0f + a;   // ALPHA = 1
}

// Kernel 3: out = x * att1[b,h,w], float4 + grid-stride (2048 blocks -> 32 waves/CU).
__global__ __launch_bounds__(256) void apply_kernel(const float* __restrict__ x,
                                                    const float* __restrict__ att1,
                                                    float* __restrict__ out) {
    const int stride = gridDim.x * blockDim.x;               // 524288
    for (int idx = blockIdx.x * blockDim.x + threadIdx.x; idx < NTOT / 4; idx += stride) {
        int e  = idx * 4;
        int b  = e >> 22;                  // / (CN*HWN)
        int hw = e & (HWN - 1);
        float4 xv = ((const float4*)x)[idx];
        float4 av = *(const float4*)(att1 + b * HWN + hw);
        float4 o = make_float4(xv.x * av.x, xv.y * av.y, xv.z * av.z, xv.w * av.w);
        ((float4*)out)[idx] = o;
    }
}

extern "C" void kernel_launch(void* const* d_in, const int* in_sizes, int n_in,
                              void* d_out, int out_size, void* d_ws, size_t ws_size,
                              hipStream_t stream) {
    const float* x  = (const float*)d_in[0];
    const float* gw = (const float*)d_in[1];
    const float* gb = (const float*)d_in[2];
    float* out = (float*)d_out;

    float* gray = (float*)d_ws;          // NPIX floats
    float* att1 = gray + NPIX;           // NPIX floats

    // Host-side DoG tap computation (pure CPU math; graph-capture safe).
    DogK dk;
    {
        double k1[25], k2[25], s1 = 0.0, s2 = 0.0;
        for (int i = 0; i < 5; ++i) {
            for (int j = 0; j < 5; ++j) {
                double di = i - 2.0, dj = j - 2.0;
                double r2 = di * di + dj * dj;
                k1[i * 5 + j] = exp(-r2 / (2.0 * 1.0 * 1.0));
                k2[i * 5 + j] = exp(-r2 / (2.0 * 2.0 * 2.0));
                s1 += k1[i * 5 + j];
                s2 += k2[i * 5 + j];
            }
        }
        for (int t = 0; t < 25; ++t)
            dk.k[t] = (float)(k1[t] / s1 - k2[t] / s2);
    }

    dim3 blk(256);
    gray_kernel<<<dim3(2048),        blk, 0, stream>>>(x, gray);
    att_fused  <<<dim3(16, 16, 8),   blk, 0, stream>>>(gray, att1, gw, gb, dk);
    apply_kernel<<<dim3(2048),       blk, 0, stream>>>(x, att1, out);
}